// Round 8
// baseline (227.929 us; speedup 1.0000x reference)
//
#include <hip/hip_runtime.h>

#define BK 16          // k-elements (fp32) per pipeline stage (64 B per row-visit)
#define NCHUNK 512     // grid = K-chunks; KC = D/NCHUNK = 512
#define THREADS 1024

typedef float f32x4 __attribute__((ext_vector_type(4)));
typedef short s16x8 __attribute__((ext_vector_type(8)));

__device__ __forceinline__ unsigned short f2bf(float f) {
  union { float f; unsigned u; } v; v.f = f;
  return (unsigned short)((v.u + 0x7FFFu + ((v.u >> 16) & 1u)) >> 16);  // RTNE
}

// k16 fragment: 4 real bf16 + 4 zeros (hi half) -> feeds the proven
// mfma_f32_16x16x32_bf16 with zero contribution from the padding.
__device__ __forceinline__ s16x8 cvt4z(f32x4 a) {
  s16x8 r;
  r[0]=(short)f2bf(a[0]); r[1]=(short)f2bf(a[1]);
  r[2]=(short)f2bf(a[2]); r[3]=(short)f2bf(a[3]);
  r[4]=0; r[5]=0; r[6]=0; r[7]=0;
  return r;
}

__global__ void __launch_bounds__(64) zero_kernel(float* out) {
  if (threadIdx.x == 0) out[0] = 0.f;
}

// Split-K GEMM: block b owns K-chunk [b*KC,(b+1)*KC), full 256x256 partial
// into ws + b*65536 (fp16).
// 1024 threads = 16 waves (4x4 grid of 64x64 wave tiles).
// LDS = 64 KiB (2-stage ring x 32 KiB) -> 2 blocks/CU, 32 waves/CU (100% occ),
// two INDEPENDENT barrier domains per CU; counted vmcnt keeps ~48 KiB/block
// in flight at all times across two k-windows.
// Reg budget: launch_bounds(1024,4) => 128 unified regs/wave; acc = 64 AGPR,
// arch VGPR ~60 (R7 measured 64+64 with a heavier loader).
// Swizzle (rule #21): linear LDS dest; per-lane global source 16B-granule
// XORed with ((row>>1)&3); ds_read applies the same XOR -> balanced banks.
__global__ void __launch_bounds__(THREADS, 4)
gemm_kernel(const float* __restrict__ V1, const float* __restrict__ V2,
            _Float16* __restrict__ ws, int D, int KC) {
  __shared__ __align__(16) float lds[2 * 2 * 256 * BK];  // 64 KiB

  const int tid  = threadIdx.x;
  const int lane = tid & 63;
  const int wid  = tid >> 6;    // 0..15
  const int wm   = wid >> 2;    // 0..3 (M)
  const int wn   = wid & 3;     // 0..3 (N)
  const int lr   = lane & 15;
  const int lg   = lane >> 4;
  const int ns   = KC / BK;     // 32

  // loader: 32 load-instrs/stage (1 KiB each: 16 rows x 64 B), 2 per wave.
  // instr idx = wid*2 + i; mat = idx>>4; rowbase = (idx&15)*16.
  // lane -> row rowbase + (lane>>2), 16B granule ((lane&3) ^ ((lane>>3)&3)).
  const int lrow = lane >> 2;                       // 0..15 row within instr
  const int gsw  = ((lane & 3) ^ ((lane >> 3) & 3)) * 4;  // swizzled float off
  const size_t chunk = (size_t)blockIdx.x * (size_t)KC;

  const float* gsrc[2];
  int ldst[2];
#pragma unroll
  for (int i = 0; i < 2; ++i) {
    const int idx = wid * 2 + i;
    const int mat = idx >> 4;
    const int rowbase = (idx & 15) * 16;
    gsrc[i] = (mat ? V2 : V1)
        + (size_t)(rowbase + lrow) * (size_t)D + chunk + (size_t)gsw;
    ldst[i] = (mat * 256 + rowbase) * BK;           // floats, wave-uniform
  }

  auto issue = [&](int t, int s) {
#pragma unroll
    for (int i = 0; i < 2; ++i) {
      const float* g = gsrc[i] + (size_t)t * BK;
      float* l = &lds[s * 2 * 256 * BK + ldst[i]];
      __builtin_amdgcn_global_load_lds(
          (const __attribute__((address_space(1))) void*)g,
          (__attribute__((address_space(3))) void*)l, 16, 0, 0);
    }
  };

  f32x4 acc[4][4];
#pragma unroll
  for (int a = 0; a < 4; ++a)
#pragma unroll
    for (int b = 0; b < 4; ++b) acc[a][b] = f32x4{0.f, 0.f, 0.f, 0.f};

  issue(0, 0);
  issue(1, 1);

  const int xsw = (lg ^ ((lr >> 1) & 3)) * 4;   // swizzled k-granule for frags

  for (int t = 0; t < ns; ++t) {
    const int s = t & 1;

    if (t + 1 < ns) asm volatile("s_waitcnt vmcnt(2)" ::: "memory");
    else            asm volatile("s_waitcnt vmcnt(0)" ::: "memory");
    __builtin_amdgcn_s_barrier();
    __builtin_amdgcn_sched_barrier(0);

    s16x8 bf[4];
#pragma unroll
    for (int nf = 0; nf < 4; ++nf) {
      int r = wn * 64 + nf * 16 + lr;
      bf[nf] = cvt4z(*(const f32x4*)&lds[((s * 2 + 1) * 256 + r) * BK + xsw]);
    }
#pragma unroll
    for (int mf = 0; mf < 4; ++mf) {
      int r = wm * 64 + mf * 16 + lr;
      s16x8 af = cvt4z(*(const f32x4*)&lds[((s * 2 + 0) * 256 + r) * BK + xsw]);
#pragma unroll
      for (int nf = 0; nf < 4; ++nf)
        acc[mf][nf] = __builtin_amdgcn_mfma_f32_16x16x32_bf16(af, bf[nf], acc[mf][nf], 0, 0, 0);
    }

    asm volatile("s_waitcnt lgkmcnt(0)" ::: "memory");
    __builtin_amdgcn_s_barrier();
    __builtin_amdgcn_sched_barrier(0);
    if (t + 2 < ns) issue(t + 2, s);
  }

  // C/D layout: col = lane&15, row = (lane>>4)*4 + reg. fp16 partials
  // (|partial| <~ 6*sqrt(512) ~ 136 << 65504; zmean err ~1e-6 — R5-R7 verified).
  _Float16* Cp = ws + (size_t)blockIdx.x * (256 * 256);
#pragma unroll
  for (int mf = 0; mf < 4; ++mf) {
    int i0 = wm * 64 + mf * 16 + lg * 4;
#pragma unroll
    for (int nf = 0; nf < 4; ++nf) {
      int j = wn * 64 + nf * 16 + lr;
#pragma unroll
      for (int v = 0; v < 4; ++v)
        Cp[(size_t)(i0 + v) * 256 + j] = (_Float16)acc[mf][nf][v];
    }
  }
}

// Sum P fp16 partials, z = dot/D, BCE vs identity labels:
//   diag: softplus(z) - z ; off-diag: softplus(z)
__global__ void __launch_bounds__(256)
loss_kernel(const _Float16* __restrict__ ws, float* __restrict__ out, int P, float invD) {
  const int i = blockIdx.x, j = threadIdx.x;
  const _Float16* base = ws + i * 256 + j;
  float s = 0.f;
#pragma unroll 8
  for (int p = 0; p < P; ++p) s += (float)base[(size_t)p * 65536];
  float z = s * invD;
  float term = log1pf(expf(z)) - (i == j ? z : 0.f);

  __shared__ float red[256];
  red[j] = term;
  __syncthreads();
  for (int st = 128; st > 0; st >>= 1) {
    if (j < st) red[j] += red[j + st];
    __syncthreads();
  }
  if (j == 0) atomicAdd(out, red[0] * (1.f / 65536.f));
}

extern "C" void kernel_launch(void* const* d_in, const int* in_sizes, int n_in,
                              void* d_out, int out_size, void* d_ws, size_t ws_size,
                              hipStream_t stream) {
  const float* V1 = (const float*)d_in[0];
  const float* V2 = (const float*)d_in[1];
  float* out = (float*)d_out;
  _Float16* ws = (_Float16*)d_ws;

  const int N = 256;
  const int D = in_sizes[0] / N;   // 262144

  int ns = NCHUNK;                 // 512 fp16 partials = 64 MB
  while (ns > 1 && (size_t)ns * 65536 * sizeof(_Float16) > ws_size) ns >>= 1;
  const int KC = D / ns;           // 512

  zero_kernel<<<1, 64, 0, stream>>>(out);
  gemm_kernel<<<ns, THREADS, 0, stream>>>(V1, V2, ws, D, KC);
  loss_kernel<<<N, 256, 0, stream>>>(ws, out, ns, 1.0f / (float)D);
}

// Round 9
// 185.364 us; speedup vs baseline: 1.2296x; 1.2296x over previous
//
#include <hip/hip_runtime.h>

#define BK 32          // fp32 k-elements per stage (128 B per row-visit)
#define LROW 36        // bf16 per LDS row: 32 data + 4 pad (72 B stride)
#define NCHUNK 512     // preferred grid = K-chunks; KC = D/NCHUNK = 512
#define THREADS 1024

typedef float f32x4 __attribute__((ext_vector_type(4)));
typedef short s16x8 __attribute__((ext_vector_type(8)));

__device__ __forceinline__ unsigned short f2bf(float f) {
  union { float f; unsigned u; } v; v.f = f;
  return (unsigned short)((v.u + 0x7FFFu + ((v.u >> 16) & 1u)) >> 16);  // RTNE
}

__global__ void __launch_bounds__(64) zero_kernel(float* out) {
  if (threadIdx.x == 0) out[0] = 0.f;
}

// Non-draining barrier: lgkmcnt(0) (my ds ops done) + s_barrier + sched pin.
// Does NOT wait vmcnt -> prefetched global loads stay in flight across it.
__device__ __forceinline__ void barrier_nodrain() {
  asm volatile("s_waitcnt lgkmcnt(0)" ::: "memory");
  __builtin_amdgcn_s_barrier();
  __builtin_amdgcn_sched_barrier(0);
}

// Split-K GEMM: block b owns K-chunk [b*KC,(b+1)*KC), computes the full
// 256x256 partial into ws + b*65536 (fp16).
// 1024 threads = 16 waves (4x4 grid of 64x64 wave tiles; acc = 64 regs).
// LDS = 72 KiB: ring-2 x [mat][256 rows][36 bf16] -> 2 blocks/CU (144 KiB),
// two independent barrier domains per CU (R8: 2nd stream lifted raw HBM
// service 2.1 -> 3.0 TB/s). BK=32 restores 128 B-aligned 128 B row-visits
// (R8's BK=16/64 B visits doubled FETCH_SIZE via line over-fetch).
// Staging: reg (4x float4/thread, R1's proven 8-lanes-per-row coalescing),
// fp32->bf16 cvt in regs, ds_write_b64. Single lgkm-only barrier per stage.
__global__ void __launch_bounds__(THREADS, 4)
gemm_kernel(const float* __restrict__ V1, const float* __restrict__ V2,
            _Float16* __restrict__ ws, int D, int KC) {
  __shared__ __align__(16) unsigned short lds[2 * 2 * 256 * LROW];  // 72 KiB

  const int tid  = threadIdx.x;
  const int lane = tid & 63;
  const int wid  = tid >> 6;    // 0..15
  const int wm   = wid >> 2;    // 0..3 (M)
  const int wn   = wid & 3;     // 0..3 (N)
  const int lr   = lane & 15;
  const int lg   = lane >> 4;
  const int ns   = KC / BK;     // 16 at KC=512

  // staging: thread covers 4 row-visits (idx = rbase + 128v), 16 B seg c8.
  // Per load instruction a wave covers 8 rows x 128 B fully -> clean lines.
  const int c8    = tid & 7;
  const int rbase = tid >> 3;   // 0..127
  const float* gsrc[4];
  int obase[4];
#pragma unroll
  for (int v = 0; v < 4; ++v) {
    const int idx = rbase + 128 * v;   // 0..511
    const int mat = idx >> 8;
    const int row = idx & 255;
    gsrc[v] = (mat ? V2 : V1)
        + (size_t)row * (size_t)D
        + (size_t)blockIdx.x * (size_t)KC + (size_t)c8 * 4;
    obase[v] = (mat * 256 + row) * LROW + c8 * 4;   // ushort units
  }

  f32x4 acc[4][4];
#pragma unroll
  for (int a = 0; a < 4; ++a)
#pragma unroll
    for (int b = 0; b < 4; ++b) acc[a][b] = f32x4{0.f, 0.f, 0.f, 0.f};

  float4 sa[4];

  auto issue = [&](int t) {
#pragma unroll
    for (int v = 0; v < 4; ++v)
      sa[v] = *(const float4*)(gsrc[v] + (size_t)t * BK);
  };
  auto lwrite = [&](int buf) {
    const int bo = buf * (2 * 256 * LROW);
#pragma unroll
    for (int v = 0; v < 4; ++v) {
      ushort4 w;
      w.x = f2bf(sa[v].x); w.y = f2bf(sa[v].y);
      w.z = f2bf(sa[v].z); w.w = f2bf(sa[v].w);
      *(ushort4*)&lds[bo + obase[v]] = w;
    }
  };

  issue(0);
  lwrite(0);
  if (ns > 1) issue(1);
  barrier_nodrain();

  for (int t = 0; t < ns; ++t) {
    const int buf = t & 1;

    s16x8 bf[4];
#pragma unroll
    for (int nf = 0; nf < 4; ++nf) {
      int r = wn * 64 + nf * 16 + lr;
      bf[nf] = *(const s16x8*)&lds[((buf * 2 + 1) * 256 + r) * LROW + lg * 8];
    }
#pragma unroll
    for (int mf = 0; mf < 4; ++mf) {
      int r = wm * 64 + mf * 16 + lr;
      s16x8 af = *(const s16x8*)&lds[((buf * 2 + 0) * 256 + r) * LROW + lg * 8];
#pragma unroll
      for (int nf = 0; nf < 4; ++nf)
        acc[mf][nf] = __builtin_amdgcn_mfma_f32_16x16x32_bf16(af, bf[nf], acc[mf][nf], 0, 0, 0);
    }

    if (t + 1 < ns) {
      lwrite(buf ^ 1);               // reg-dep waits only stage t+1's loads
      if (t + 2 < ns) issue(t + 2);  // stays in flight across the barrier
    }
    barrier_nodrain();
  }

  // C/D layout: col = lane&15, row = (lane>>4)*4 + reg. fp16 partials
  // (|partial| <~ 6*sqrt(512) ~ 136 << 65504; zmean err ~1e-6 — R5-R8 verified).
  _Float16* Cp = ws + (size_t)blockIdx.x * (256 * 256);
#pragma unroll
  for (int mf = 0; mf < 4; ++mf) {
    int i0 = wm * 64 + mf * 16 + lg * 4;
#pragma unroll
    for (int nf = 0; nf < 4; ++nf) {
      int j = wn * 64 + nf * 16 + lr;
#pragma unroll
      for (int v = 0; v < 4; ++v)
        Cp[(size_t)(i0 + v) * 256 + j] = (_Float16)acc[mf][nf][v];
    }
  }
}

// Sum P fp16 partials, z = dot/D, BCE vs identity labels:
//   diag: softplus(z) - z ; off-diag: softplus(z)
__global__ void __launch_bounds__(256)
loss_kernel(const _Float16* __restrict__ ws, float* __restrict__ out, int P, float invD) {
  const int i = blockIdx.x, j = threadIdx.x;
  const _Float16* base = ws + i * 256 + j;
  float s = 0.f;
#pragma unroll 8
  for (int p = 0; p < P; ++p) s += (float)base[(size_t)p * 65536];
  float z = s * invD;
  float term = log1pf(expf(z)) - (i == j ? z : 0.f);

  __shared__ float red[256];
  red[j] = term;
  __syncthreads();
  for (int st = 128; st > 0; st >>= 1) {
    if (j < st) red[j] += red[j + st];
    __syncthreads();
  }
  if (j == 0) atomicAdd(out, red[0] * (1.f / 65536.f));
}

extern "C" void kernel_launch(void* const* d_in, const int* in_sizes, int n_in,
                              void* d_out, int out_size, void* d_ws, size_t ws_size,
                              hipStream_t stream) {
  const float* V1 = (const float*)d_in[0];
  const float* V2 = (const float*)d_in[1];
  float* out = (float*)d_out;
  _Float16* ws = (_Float16*)d_ws;

  const int N = 256;
  const int D = in_sizes[0] / N;   // 262144

  int ns = NCHUNK;                 // 512 fp16 partials = 64 MB
  while (ns > 1 && (size_t)ns * 65536 * sizeof(_Float16) > ws_size) ns >>= 1;
  const int KC = D / ns;           // 512

  zero_kernel<<<1, 64, 0, stream>>>(out);
  gemm_kernel<<<ns, THREADS, 0, stream>>>(V1, V2, ws, D, KC);
  loss_kernel<<<N, 256, 0, stream>>>(ws, out, ns, 1.0f / (float)D);
}

// Round 10
// 182.352 us; speedup vs baseline: 1.2499x; 1.0165x over previous
//
#include <hip/hip_runtime.h>

#define BK 32          // fp32 k-elements per stage (128 B per row-visit)
#define NCHUNK 256     // K-chunks; KC = D/NCHUNK = 1024
#define THREADS 1024

typedef float f32x4 __attribute__((ext_vector_type(4)));
typedef short s16x8 __attribute__((ext_vector_type(8)));

__device__ __forceinline__ unsigned short f2bf(float f) {
  union { float f; unsigned u; } v; v.f = f;
  return (unsigned short)((v.u + 0x7FFFu + ((v.u >> 16) & 1u)) >> 16);  // RTNE
}

__device__ __forceinline__ s16x8 cvt8(f32x4 a, f32x4 b) {
  s16x8 r;
  r[0]=(short)f2bf(a[0]); r[1]=(short)f2bf(a[1]); r[2]=(short)f2bf(a[2]); r[3]=(short)f2bf(a[3]);
  r[4]=(short)f2bf(b[0]); r[5]=(short)f2bf(b[1]); r[6]=(short)f2bf(b[2]); r[7]=(short)f2bf(b[3]);
  return r;
}

__global__ void __launch_bounds__(64) zero_kernel(float* out) {
  if (threadIdx.x == 0) out[0] = 0.f;
}

// Split-K GEMM, quadrant-split: chunk c (K-window [c*KC,(c+1)*KC)) is computed
// by 4 blocks, quadrant (qm,qn) covering C[qm*128..+128][qn*128..+128].
// Each block stages 256 rows (128 of V1 + 128 of V2) x 128 B per stage via
// global_load_lds; fp32 ring-2 = 64 KiB -> 2 blocks/CU. Counted vmcnt(2)
// keeps the VMEM queue NON-EMPTY at all times (R8 proved this doubles
// sustained service 1.5 -> 3.0 TB/s vs reg-dep sawtooth; R9 confirmed the
// converse). BK=32 gives 128 B-aligned visits (R8's 64 B visits over-fetched
// 2x). Quadrants of a chunk are placed 8 blockIdx apart -> same XCD under
// round-robin -> the 2x tile re-read is served by that XCD's private L2.
// Swizzle (rule #21 involution, from R7): linear LDS dest; per-lane global
// source granule (lane&7)^(lane>>3); frag reads XOR granule with (row&7).
__global__ void __launch_bounds__(THREADS, 4)
gemm_kernel(const float* __restrict__ V1, const float* __restrict__ V2,
            _Float16* __restrict__ ws, int D, int KC, int P) {
  __shared__ __align__(16) float lds[2 * 256 * BK];  // 64 KiB

  const int tid  = threadIdx.x;
  const int lane = tid & 63;
  const int wid  = tid >> 6;    // 0..15
  const int wm   = wid >> 2;    // 0..3 (M within 128)
  const int wn   = wid & 3;     // 0..3 (N within 128)
  const int lr   = lane & 15;
  const int lg   = lane >> 4;
  const int ns   = KC / BK;     // 32

  // block -> (chunk, quadrant): quadrants spaced 8 apart (same XCD),
  // within a 32-index window (temporally adjacent).
  const int g  = blockIdx.x;
  int c, q;
  if ((P & 7) == 0) { c = ((g >> 5) << 3) | (g & 7); q = (g >> 3) & 3; }
  else              { c = g >> 2;                    q = g & 3; }
  const int qm = q >> 1, qn = q & 1;

  // loader: 32 DMA instrs/stage (8 rows x 128 B each); wave w owns 2.
  // instr idx: LDS rows idx*8..+8; idx<16 -> V1 panel, else V2 panel.
  const int sw = ((lane & 7) ^ (lane >> 3)) * 4;   // swizzled src float-offset
  const float* gsrc[2];
  int ldst[2];
#pragma unroll
  for (int i = 0; i < 2; ++i) {
    const int idx = wid * 2 + i;            // 0..31
    const int mat = idx >> 4;
    const int grow = (mat ? qn : qm) * 128 + (idx & 15) * 8 + (lane >> 3);
    gsrc[i] = (mat ? V2 : V1)
        + (size_t)grow * (size_t)D + (size_t)c * (size_t)KC + (size_t)sw;
    ldst[i] = idx * 8 * BK;                 // floats, wave-uniform
  }

  auto issue = [&](int t, int s) {
#pragma unroll
    for (int i = 0; i < 2; ++i) {
      const float* gp = gsrc[i] + (size_t)t * BK;
      float* l = &lds[s * 256 * BK + ldst[i]];
      __builtin_amdgcn_global_load_lds(
          (const __attribute__((address_space(1))) void*)gp,
          (__attribute__((address_space(3))) void*)l, 16, 0, 0);
    }
  };

  f32x4 acc[2][2];
#pragma unroll
  for (int a = 0; a < 2; ++a)
#pragma unroll
    for (int b = 0; b < 2; ++b) acc[a][b] = f32x4{0.f, 0.f, 0.f, 0.f};

  issue(0, 0);
  issue(1, 1);

  const int xr = lr & 7;   // row-XOR for frag reads (row&7 == lr&7)

  for (int t = 0; t < ns; ++t) {
    const int s = t & 1;

    if (t + 1 < ns) asm volatile("s_waitcnt vmcnt(2)" ::: "memory");
    else            asm volatile("s_waitcnt vmcnt(0)" ::: "memory");
    __builtin_amdgcn_s_barrier();
    __builtin_amdgcn_sched_barrier(0);

    const float* sb = &lds[s * 256 * BK];
    s16x8 bf[2];
#pragma unroll
    for (int nf = 0; nf < 2; ++nf) {
      int r = 128 + wn * 32 + nf * 16 + lr;
      f32x4 lo = *(const f32x4*)&sb[r * BK + (((2 * lg + 0) ^ xr) * 4)];
      f32x4 hi = *(const f32x4*)&sb[r * BK + (((2 * lg + 1) ^ xr) * 4)];
      bf[nf] = cvt8(lo, hi);
    }
#pragma unroll
    for (int mf = 0; mf < 2; ++mf) {
      int r = wm * 32 + mf * 16 + lr;
      f32x4 lo = *(const f32x4*)&sb[r * BK + (((2 * lg + 0) ^ xr) * 4)];
      f32x4 hi = *(const f32x4*)&sb[r * BK + (((2 * lg + 1) ^ xr) * 4)];
      s16x8 af = cvt8(lo, hi);
#pragma unroll
      for (int nf = 0; nf < 2; ++nf)
        acc[mf][nf] = __builtin_amdgcn_mfma_f32_16x16x32_bf16(af, bf[nf], acc[mf][nf], 0, 0, 0);
    }

    asm volatile("s_waitcnt lgkmcnt(0)" ::: "memory");
    __builtin_amdgcn_s_barrier();
    __builtin_amdgcn_sched_barrier(0);
    if (t + 2 < ns) issue(t + 2, s);
  }

  // C/D layout: col = lane&15, row = (lane>>4)*4 + reg. fp16 partials
  // (|partial| <~ 6*sqrt(1024) ~ 200 << 65504; zmean err ~1e-6, R5-R9 verified).
  _Float16* Cp = ws + (size_t)c * (256 * 256);
#pragma unroll
  for (int mf = 0; mf < 2; ++mf) {
    int i0 = qm * 128 + wm * 32 + mf * 16 + lg * 4;
#pragma unroll
    for (int nf = 0; nf < 2; ++nf) {
      int j = qn * 128 + wn * 32 + nf * 16 + lr;
#pragma unroll
      for (int v = 0; v < 2 * 2; ++v)
        Cp[(size_t)(i0 + v) * 256 + j] = (_Float16)acc[mf][nf][v];
    }
  }
}

// Sum P fp16 partials, z = dot/D, BCE vs identity labels:
//   diag: softplus(z) - z ; off-diag: softplus(z)
__global__ void __launch_bounds__(256)
loss_kernel(const _Float16* __restrict__ ws, float* __restrict__ out, int P, float invD) {
  const int i = blockIdx.x, j = threadIdx.x;
  const _Float16* base = ws + i * 256 + j;
  float s = 0.f;
#pragma unroll 8
  for (int p = 0; p < P; ++p) s += (float)base[(size_t)p * 65536];
  float z = s * invD;
  float term = log1pf(expf(z)) - (i == j ? z : 0.f);

  __shared__ float red[256];
  red[j] = term;
  __syncthreads();
  for (int st = 128; st > 0; st >>= 1) {
    if (j < st) red[j] += red[j + st];
    __syncthreads();
  }
  if (j == 0) atomicAdd(out, red[0] * (1.f / 65536.f));
}

extern "C" void kernel_launch(void* const* d_in, const int* in_sizes, int n_in,
                              void* d_out, int out_size, void* d_ws, size_t ws_size,
                              hipStream_t stream) {
  const float* V1 = (const float*)d_in[0];
  const float* V2 = (const float*)d_in[1];
  float* out = (float*)d_out;
  _Float16* ws = (_Float16*)d_ws;

  const int N = 256;
  const int D = in_sizes[0] / N;   // 262144

  int P = NCHUNK;                  // 256 fp16 partials = 32 MB
  while (P > 1 && (size_t)P * 65536 * sizeof(_Float16) > ws_size) P >>= 1;
  const int KC = D / P;            // 1024

  zero_kernel<<<1, 64, 0, stream>>>(out);
  gemm_kernel<<<4 * P, THREADS, 0, stream>>>(V1, V2, ws, D, KC, P);
  loss_kernel<<<N, 256, 0, stream>>>(ws, out, P, 1.0f / (float)D);
}